// Round 1
// 580.300 us; speedup vs baseline: 1.0556x; 1.0556x over previous
//
#include <hip/hip_runtime.h>
#include <hip/hip_bf16.h>
#include <math.h>

// SpKBGAT: N=50000, D=200, R=500, NHID=100, H=2, OD=200, E=150000, ENH=30000.
// R9: latency-bound gathers -> (1) head-interleaved padded pB/x1A2 rows with
// attention scalars packed in the row pad (one random stream per edge),
// (2) 2-edge unrolled gather loops (2x memory-level parallelism),
// (3) int2 CSR entries (8B/edge).
#define DD   200
#define NHID 100
#define OD   200
#define KP   224   // padded K (7 chunks of 32)
#define PBS  224   // padded row stride (bf16 elems) for pB / x1A2: 448 B, 64B-aligned
                   // layout: [0..99]=h0 feats, [100..199]=h1 feats, bytes 400..407 = s2 floats

typedef __attribute__((ext_vector_type(8))) short short8;
typedef __attribute__((ext_vector_type(4))) float f32x4;

static inline int cdiv(int a, int b) { return (a + b - 1) / b; }

__device__ inline float toF(float x) { return x; }
__device__ inline float toF(__hip_bfloat16 x) { return __bfloat162float(x); }
__device__ inline void storeC(float v, float* p) { *p = v; }
__device__ inline void storeC(float v, __hip_bfloat16* p) { *p = __float2bfloat16(v); }
__device__ inline short bf16s(float f) {
    __hip_bfloat16 h = __float2bfloat16(f);
    short s; __builtin_memcpy(&s, &h, 2); return s;
}

// -------- per-row inverse L2 norm (f32), wave per row --------
__global__ __launch_bounds__(256)
void rownorm_inv_k(const float* __restrict__ in, float* __restrict__ sc, int M, int Dd)
{
    int wave = (blockIdx.x * blockDim.x + threadIdx.x) >> 6;
    int lane = threadIdx.x & 63;
    if (wave >= M) return;
    float ss = 0.f;
    for (int k = lane; k < Dd; k += 64) {
        float x = in[(size_t)wave * Dd + k];
        ss += x * x;
    }
    for (int o = 32; o > 0; o >>= 1) ss += __shfl_down(ss, o);
    if (lane == 0) sc[wave] = 1.f / fmaxf(sqrtf(ss), 1e-12f);
}

// -------- B-panel prep: bf16 [col][KP], zero-padded --------
__global__ void prep_bt_l1(const float* __restrict__ ah, __hip_bfloat16* __restrict__ Bt)
{
    int c = blockIdx.x, k = threadIdx.x;
    if (k >= KP) return;
    int seg = c / 100, idx = c - seg * 100;
    int h = seg & 1, off = (seg >> 1) * 200;
    float v = (k < 200) ? ah[(size_t)(h * 100 + idx) * 600 + off + k] : 0.f;
    Bt[(size_t)c * KP + k] = __float2bfloat16(v);
}
__global__ void prep_bt_l2(const float* __restrict__ ao, __hip_bfloat16* __restrict__ Bt)
{
    int c = blockIdx.x, k = threadIdx.x;
    if (k >= KP) return;
    int row = (c < 200) ? c : c - 200;
    int off = (c < 200) ? 0 : 200;
    float v = (k < 200) ? ao[(size_t)row * 600 + off + k] : 0.f;
    Bt[(size_t)c * KP + k] = __float2bfloat16(v);
}
__global__ void prep_bt_fin(const float* __restrict__ W, __hip_bfloat16* __restrict__ Bt)
{
    int c = blockIdx.x, k = threadIdx.x;
    if (k >= KP) return;
    float v = (c < 200 && k < 200) ? W[(size_t)k * 200 + c] : 0.f;
    Bt[(size_t)c * KP + k] = __float2bfloat16(v);
}

// -------- layer-1 fused (both heads): 25 tiles = xa1_h0|xa1_h1|xa2_h0|xa2_h1
__global__ __launch_bounds__(256)
void l1_both_k(const float* __restrict__ ent, const float* __restrict__ nscale,
               const __hip_bfloat16* __restrict__ Bt,  // [400][KP]
               const float* __restrict__ a2h,          // [2][100]
               __hip_bfloat16* __restrict__ x1,        // [N][KP] (cols 0-199)
               __hip_bfloat16* __restrict__ pB,        // [N][PBS] interleaved + s2 in pad
               float* __restrict__ s1,                 // [2][N]
               int M)
{
    int tid = threadIdx.x, wave = tid >> 6, lane = tid & 63;
    int quad = lane >> 4, l16 = lane & 15;
    int m0 = blockIdx.x * 64;
    int arow = m0 + wave * 16 + l16;
    bool rok = arow < M;
    float nsc = rok ? nscale[arow] : 0.f;
    const float* arp = ent + (size_t)arow * DD;

    f32x4 acc[25];
#pragma unroll
    for (int t = 0; t < 25; t++) acc[t] = (f32x4){0.f, 0.f, 0.f, 0.f};

    for (int ch = 0; ch < 7; ch++) {
        int kb = ch * 32 + quad * 8;
        float av[8];
        if (rok && kb + 8 <= DD) {
            const float4* p = (const float4*)(arp + kb);
            float4 u0 = p[0], u1 = p[1];
            av[0] = u0.x; av[1] = u0.y; av[2] = u0.z; av[3] = u0.w;
            av[4] = u1.x; av[5] = u1.y; av[6] = u1.z; av[7] = u1.w;
        } else {
#pragma unroll
            for (int j = 0; j < 8; j++) av[j] = (rok && kb + j < DD) ? arp[kb + j] : 0.f;
        }
        short8 a;
#pragma unroll
        for (int j = 0; j < 8; j++) a[j] = bf16s(av[j] * nsc);
        const __hip_bfloat16* bp = Bt + (size_t)l16 * KP + kb;
#pragma unroll
        for (int t = 0; t < 25; t++) {
            short8 b = *(const short8*)(bp + (size_t)t * 16 * KP);
            acc[t] = __builtin_amdgcn_mfma_f32_16x16x32_bf16(a, b, acc[t], 0, 0, 0);
        }
    }

    int orow = m0 + wave * 16 + quad * 4;
    float d0[4] = {0,0,0,0}, d1[4] = {0,0,0,0}, d2[4] = {0,0,0,0}, d3[4] = {0,0,0,0};
#pragma unroll
    for (int t = 0; t < 25; t++) {
        int c = t * 16 + l16;
        int seg = c / 100, idx = c - seg * 100;
        float w = a2h[(seg & 1) * 100 + idx];
#pragma unroll
        for (int i = 0; i < 4; i++) {
            float v = acc[t][i];
            float vw = v * w;
            if (seg == 0) d0[i] += vw;
            else if (seg == 1) d1[i] += vw;
            else if (seg == 2) d2[i] += vw;
            else d3[i] += vw;
            int gm = orow + i;
            if (gm < M) {
                if (seg < 2) x1[(size_t)gm * KP + c] = __float2bfloat16(v);
                else pB[(size_t)gm * PBS + (seg - 2) * 100 + idx] = __float2bfloat16(v);
            }
        }
    }
#pragma unroll
    for (int msk = 1; msk < 16; msk <<= 1)
#pragma unroll
        for (int i = 0; i < 4; i++) {
            d0[i] += __shfl_xor(d0[i], msk);
            d1[i] += __shfl_xor(d1[i], msk);
            d2[i] += __shfl_xor(d2[i], msk);
            d3[i] += __shfl_xor(d3[i], msk);
        }
    if (l16 == 0)
#pragma unroll
        for (int i = 0; i < 4; i++) {
            int gm = orow + i;
            if (gm < M) {
                s1[gm] = d0[i]; s1[M + gm] = d1[i];
                float2 sv; sv.x = d2[i]; sv.y = d3[i];
                *(float2*)((char*)pB + (size_t)gm * (PBS * 2) + 400) = sv;
            }
        }
}

// -------- layer-2 fused: 25 tiles = x1A1 (f32 -> out_ent) | x1A2 (bf16) ----
__global__ __launch_bounds__(256)
void l2_proj_k(const __hip_bfloat16* __restrict__ x1,  // [N][KP]
               const __hip_bfloat16* __restrict__ Bt,  // [400][KP]
               const float* __restrict__ a2o,          // [200]
               float* __restrict__ x1A1,               // [N][200] (out_ent)
               __hip_bfloat16* __restrict__ x1A2,      // [N][PBS], s2 float in pad
               float* __restrict__ s1, int M)
{
    int tid = threadIdx.x, wave = tid >> 6, lane = tid & 63;
    int quad = lane >> 4, l16 = lane & 15;
    int m0 = blockIdx.x * 64;
    int arow = m0 + wave * 16 + l16;
    bool rok = arow < M;
    const __hip_bfloat16* arp = x1 + (size_t)arow * KP;

    f32x4 acc[25];
#pragma unroll
    for (int t = 0; t < 25; t++) acc[t] = (f32x4){0.f, 0.f, 0.f, 0.f};

    for (int ch = 0; ch < 7; ch++) {
        int kb = ch * 32 + quad * 8;
        short8 a = (short8){0,0,0,0,0,0,0,0};
        if (rok) a = *(const short8*)(arp + kb);
        const __hip_bfloat16* bp = Bt + (size_t)l16 * KP + kb;
#pragma unroll
        for (int t = 0; t < 25; t++) {
            short8 b = *(const short8*)(bp + (size_t)t * 16 * KP);
            acc[t] = __builtin_amdgcn_mfma_f32_16x16x32_bf16(a, b, acc[t], 0, 0, 0);
        }
    }

    int orow = m0 + wave * 16 + quad * 4;
    float dA[4] = {0,0,0,0}, dB[4] = {0,0,0,0};
#pragma unroll
    for (int t = 0; t < 25; t++) {
        int c = t * 16 + l16;
        bool first = c < 200;
        int cc = first ? c : c - 200;
        float w = a2o[cc];
#pragma unroll
        for (int i = 0; i < 4; i++) {
            float v = acc[t][i];
            int gm = orow + i;
            if (first) {
                dA[i] += v * w;
                if (gm < M) x1A1[(size_t)gm * OD + c] = v;
            } else {
                dB[i] += v * w;
                if (gm < M) x1A2[(size_t)gm * PBS + cc] = __float2bfloat16(v);
            }
        }
    }
#pragma unroll
    for (int msk = 1; msk < 16; msk <<= 1)
#pragma unroll
        for (int i = 0; i < 4; i++) {
            dA[i] += __shfl_xor(dA[i], msk);
            dB[i] += __shfl_xor(dB[i], msk);
        }
    if (l16 == 0)
#pragma unroll
        for (int i = 0; i < 4; i++) {
            int gm = orow + i;
            if (gm < M) {
                s1[gm] = dA[i];
                *(float*)((char*)x1A2 + (size_t)gm * (PBS * 2) + 400) = dB[i];
            }
        }
}

// -------- final: out_ent = l2norm(out_ent + (ent*nscale) @ W_ent) ---------
__global__ __launch_bounds__(256)
void final_mfma_k(const float* __restrict__ ent, const float* __restrict__ nscale,
                  const __hip_bfloat16* __restrict__ Bt,  // [208][KP]
                  float* __restrict__ outent, int M)
{
    int tid = threadIdx.x, wave = tid >> 6, lane = tid & 63;
    int quad = lane >> 4, l16 = lane & 15;
    int m0 = blockIdx.x * 64;
    int arow = m0 + wave * 16 + l16;
    bool rok = arow < M;
    float nsc = rok ? nscale[arow] : 0.f;
    const float* arp = ent + (size_t)arow * DD;

    f32x4 acc[13];
#pragma unroll
    for (int t = 0; t < 13; t++) acc[t] = (f32x4){0.f, 0.f, 0.f, 0.f};

    for (int ch = 0; ch < 7; ch++) {
        int kb = ch * 32 + quad * 8;
        float av[8];
        if (rok && kb + 8 <= DD) {
            const float4* p = (const float4*)(arp + kb);
            float4 u0 = p[0], u1 = p[1];
            av[0] = u0.x; av[1] = u0.y; av[2] = u0.z; av[3] = u0.w;
            av[4] = u1.x; av[5] = u1.y; av[6] = u1.z; av[7] = u1.w;
        } else {
#pragma unroll
            for (int j = 0; j < 8; j++) av[j] = (rok && kb + j < DD) ? arp[kb + j] : 0.f;
        }
        short8 a;
#pragma unroll
        for (int j = 0; j < 8; j++) a[j] = bf16s(av[j] * nsc);
        const __hip_bfloat16* bp = Bt + (size_t)l16 * KP + kb;
#pragma unroll
        for (int t = 0; t < 13; t++) {
            short8 b = *(const short8*)(bp + (size_t)t * 16 * KP);
            acc[t] = __builtin_amdgcn_mfma_f32_16x16x32_bf16(a, b, acc[t], 0, 0, 0);
        }
    }

    int orow = m0 + wave * 16 + quad * 4;
    float ss[4] = {0.f, 0.f, 0.f, 0.f};
#pragma unroll
    for (int t = 0; t < 13; t++) {
        int gn = t * 16 + l16;
#pragma unroll
        for (int i = 0; i < 4; i++) {
            int gm = orow + i;
            float v = 0.f;
            if (gn < OD && gm < M) v = acc[t][i] + outent[(size_t)gm * OD + gn];
            acc[t][i] = v;
            ss[i] += v * v;
        }
    }
#pragma unroll
    for (int msk = 1; msk < 16; msk <<= 1)
#pragma unroll
        for (int i = 0; i < 4; i++) ss[i] += __shfl_xor(ss[i], msk);
    float scl[4];
#pragma unroll
    for (int i = 0; i < 4; i++) scl[i] = 1.f / fmaxf(sqrtf(ss[i]), 1e-12f);
#pragma unroll
    for (int t = 0; t < 13; t++) {
        int gn = t * 16 + l16;
        if (gn >= OD) continue;
#pragma unroll
        for (int i = 0; i < 4; i++) {
            int gm = orow + i;
            if (gm < M) outent[(size_t)gm * OD + gn] = acc[t][i] * scl[i];
        }
    }
}

// -------- generic MFMA GEMM (small R-sized matmuls) --------
#define KPAD 48
template<bool BTr, typename AT, typename CT>
__global__ __launch_bounds__(256)
void gemm_mfma_k(const AT* __restrict__ A, int lda, const float* __restrict__ ascale,
                 const float* __restrict__ B, int ldb, int colOff,
                 CT* __restrict__ C, int ldc, int M, int Nc, int K)
{
    __shared__ __align__(16) __hip_bfloat16 As[64][KPAD];
    __shared__ __align__(16) __hip_bfloat16 Bs[64][KPAD];
    int tid  = threadIdx.x;
    int wave = tid >> 6, lane = tid & 63;
    int quad = lane >> 4, l16 = lane & 15;
    int n0 = blockIdx.x * 64, m0 = blockIdx.y * 64;
    f32x4 acc[4];
#pragma unroll
    for (int t = 0; t < 4; t++) acc[t] = (f32x4){0.f, 0.f, 0.f, 0.f};

    for (int k0 = 0; k0 < K; k0 += 32) {
        {
            int m = tid >> 2, kc = (tid & 3) * 8;
            int gm = m0 + m;
            float scale = (ascale && gm < M) ? ascale[gm] : 1.f;
#pragma unroll
            for (int j = 0; j < 8; j++) {
                int gk = k0 + kc + j;
                float v = 0.f;
                if (gm < M && gk < K) v = toF(A[(size_t)gm * lda + gk]) * scale;
                As[m][kc + j] = __float2bfloat16(v);
            }
        }
        if (BTr) {
            int n = tid >> 2, kc = (tid & 3) * 8;
            int gn = n0 + n;
#pragma unroll
            for (int j = 0; j < 8; j++) {
                int gk = k0 + kc + j;
                float v = 0.f;
                if (gn < Nc && gk < K) v = B[(size_t)gn * ldb + colOff + gk];
                Bs[n][kc + j] = __float2bfloat16(v);
            }
        } else {
            int n = tid & 63, kq = tid >> 6;
            int gn = n0 + n;
#pragma unroll
            for (int j = 0; j < 8; j++) {
                int gk = k0 + kq * 8 + j;
                float v = 0.f;
                if (gn < Nc && gk < K) v = B[(size_t)gk * ldb + gn];
                Bs[n][kq * 8 + j] = __float2bfloat16(v);
            }
        }
        __syncthreads();
        short8 a = *(const short8*)&As[wave * 16 + l16][quad * 8];
#pragma unroll
        for (int t = 0; t < 4; t++) {
            short8 b = *(const short8*)&Bs[t * 16 + l16][quad * 8];
            acc[t] = __builtin_amdgcn_mfma_f32_16x16x32_bf16(a, b, acc[t], 0, 0, 0);
        }
        __syncthreads();
    }
#pragma unroll
    for (int t = 0; t < 4; t++) {
        int gn = n0 + t * 16 + l16;
        if (gn >= Nc) continue;
#pragma unroll
        for (int i = 0; i < 4; i++) {
            int gm = m0 + wave * 16 + quad * 4 + i;
            if (gm < M) storeC(acc[t][i], &C[(size_t)gm * ldc + gn]);
        }
    }
}

// -------- row-dot (srel) --------
template<typename T>
__global__ __launch_bounds__(256)
void rowdot_k(const T* __restrict__ mat, int ld, int coff,
              const float* __restrict__ vec,
              float* __restrict__ outp, int M, int Dd)
{
    int wave = (blockIdx.x * blockDim.x + threadIdx.x) >> 6;
    int lane = threadIdx.x & 63;
    if (wave >= M) return;
    float s = 0.f;
    for (int k = lane; k < Dd; k += 64)
        s += toF(mat[(size_t)wave * ld + coff + k]) * vec[k];
    for (int o = 32; o > 0; o >>= 1) s += __shfl_down(s, o);
    if (lane == 0) outp[wave] = s;
}

// -------- CSR build --------
__device__ inline void decode_edge(const int* __restrict__ el, int E,
                                   const int* __restrict__ etype,
                                   const int* __restrict__ tin, int e,
                                   int& dst, int& src, int& r1, int& r2)
{
    if (e < E) { dst = el[e]; src = el[E + e]; r1 = etype[e]; r2 = -1; }
    else {
        int j = e - E;
        dst = tin[j * 4 + 3]; src = tin[j * 4 + 0];
        r1 = tin[j * 4 + 1];  r2 = tin[j * 4 + 2];
    }
}

__global__ void hist_k(const int* __restrict__ el, int E, const int* __restrict__ etype,
                       const int* __restrict__ tin, int Etot, int* __restrict__ cnt)
{
    int e = blockIdx.x * blockDim.x + threadIdx.x;
    if (e >= Etot) return;
    int dst, src, r1, r2; decode_edge(el, E, etype, tin, e, dst, src, r1, r2);
    atomicAdd(&cnt[dst], 1);
}

__global__ __launch_bounds__(1024)
void scan1_k(const int* __restrict__ cnt, int* __restrict__ start,
             int* __restrict__ aux, int n)
{
    __shared__ int tmp[1024];
    int i = blockIdx.x * 1024 + threadIdx.x;
    int v = (i < n) ? cnt[i] : 0;
    tmp[threadIdx.x] = v;
    __syncthreads();
    for (int o = 1; o < 1024; o <<= 1) {
        int t = (threadIdx.x >= (unsigned)o) ? tmp[threadIdx.x - o] : 0;
        __syncthreads();
        tmp[threadIdx.x] += t;
        __syncthreads();
    }
    if (i < n) start[i] = tmp[threadIdx.x] - v;
    if (threadIdx.x == 1023) aux[blockIdx.x] = tmp[1023];
}

__global__ void scan2_k(int* __restrict__ aux, int nb)
{
    if (threadIdx.x == 0 && blockIdx.x == 0) {
        int s = 0;
        for (int i = 0; i < nb; i++) { int v = aux[i]; aux[i] = s; s += v; }
    }
}

__global__ __launch_bounds__(1024)
void scan3_k(int* __restrict__ start, const int* __restrict__ aux, int n, int Etot)
{
    int i = blockIdx.x * 1024 + threadIdx.x;
    if (i < n) start[i] += aux[blockIdx.x];
    if (i == 0) start[n] = Etot;
}

// csr entry: .x = src, .y = r1 | (r2s<<16), r2s==0xFFFF means "no r2"
__global__ void fill_k(const int* __restrict__ el, int E, const int* __restrict__ etype,
                       const int* __restrict__ tin, int Etot,
                       const int* __restrict__ start, int* __restrict__ fill,
                       int2* __restrict__ csr)
{
    int e = blockIdx.x * blockDim.x + threadIdx.x;
    if (e >= Etot) return;
    int dst, src, r1, r2; decode_edge(el, E, etype, tin, e, dst, src, r1, r2);
    int p = start[dst] + atomicAdd(&fill[dst], 1);
    unsigned r2s = (r2 >= 0) ? (unsigned)r2 : 0xFFFFu;
    csr[p] = make_int2(src, (int)((r2s << 16) | (unsigned)r1));
}

// -------- layer-1 gather (both heads), wave per dst; 2-edge unrolled -------
__global__ __launch_bounds__(256)
void gather_l1_k(const int* __restrict__ start, const int2* __restrict__ csr,
                 const float* __restrict__ s1,                // [2][N] dst-side
                 const float* __restrict__ srel2, int R_,     // [2][R]
                 const __hip_bfloat16* __restrict__ pB,       // [N][PBS] + s2 in pad
                 const float* __restrict__ rpf2,              // [2][R][100]
                 __hip_bfloat16* __restrict__ x1, int N)      // [N][KP]
{
    int n = (blockIdx.x * blockDim.x + threadIdx.x) >> 6;
    int lane = threadIdx.x & 63;
    if (n >= N) return;
    int b0 = start[n], b1 = start[n + 1];
    float s1h0 = s1[n], s1h1 = s1[N + n];
    float rs0 = 0.f, rs1 = 0.f;
    float a00 = 0.f, a01 = 0.f, a10 = 0.f, a11 = 0.f;
    int k0 = lane, k1 = lane + 64;
    bool k1ok = k1 < 100;
    const float* rph1 = rpf2 + (size_t)R_ * 100;

    int idx = b0;
    for (; idx + 1 < b1; idx += 2) {
        int2 eA = csr[idx], eB = csr[idx + 1];
        unsigned eyA = (unsigned)eA.y, eyB = (unsigned)eB.y;
        int r1A = (int)(eyA & 0xFFFFu), r1B = (int)(eyB & 0xFFFFu);
        unsigned r2A = eyA >> 16, r2B = eyB >> 16;
        const __hip_bfloat16* rA = pB + (size_t)eA.x * PBS;
        const __hip_bfloat16* rB = pB + (size_t)eB.x * PBS;
        float2 sA = *(const float2*)(rA + 200);
        float2 sB = *(const float2*)(rB + 200);
        float vA00 = toF(rA[k0]), vA10 = toF(rA[100 + k0]);
        float vB00 = toF(rB[k0]), vB10 = toF(rB[100 + k0]);
        float vA01 = 0.f, vA11 = 0.f, vB01 = 0.f, vB11 = 0.f;
        if (k1ok) {
            vA01 = toF(rA[k1]); vA11 = toF(rA[100 + k1]);
            vB01 = toF(rB[k1]); vB11 = toF(rB[100 + k1]);
        }
        const float* qA0 = rpf2 + (size_t)r1A * 100;
        const float* qA1 = rph1 + (size_t)r1A * 100;
        const float* qB0 = rpf2 + (size_t)r1B * 100;
        const float* qB1 = rph1 + (size_t)r1B * 100;
        float srA0 = srel2[r1A], srA1 = srel2[R_ + r1A];
        float srB0 = srel2[r1B], srB1 = srel2[R_ + r1B];
        vA00 += qA0[k0]; vA10 += qA1[k0];
        vB00 += qB0[k0]; vB10 += qB1[k0];
        if (k1ok) {
            vA01 += qA0[k1]; vA11 += qA1[k1];
            vB01 += qB0[k1]; vB11 += qB1[k1];
        }
        if (r2A != 0xFFFFu) {
            const float* t0 = rpf2 + (size_t)r2A * 100;
            const float* t1 = rph1 + (size_t)r2A * 100;
            srA0 += srel2[(int)r2A]; srA1 += srel2[R_ + (int)r2A];
            vA00 += t0[k0]; vA10 += t1[k0];
            if (k1ok) { vA01 += t0[k1]; vA11 += t1[k1]; }
        }
        if (r2B != 0xFFFFu) {
            const float* t0 = rpf2 + (size_t)r2B * 100;
            const float* t1 = rph1 + (size_t)r2B * 100;
            srB0 += srel2[(int)r2B]; srB1 += srel2[R_ + (int)r2B];
            vB00 += t0[k0]; vB10 += t1[k0];
            if (k1ok) { vB01 += t0[k1]; vB11 += t1[k1]; }
        }
        float zA0 = s1h0 + sA.x + srA0, zA1 = s1h1 + sA.y + srA1;
        float zB0 = s1h0 + sB.x + srB0, zB1 = s1h1 + sB.y + srB1;
        float wA0 = expf(-(zA0 > 0.f ? zA0 : 0.2f * zA0));
        float wA1 = expf(-(zA1 > 0.f ? zA1 : 0.2f * zA1));
        float wB0 = expf(-(zB0 > 0.f ? zB0 : 0.2f * zB0));
        float wB1 = expf(-(zB1 > 0.f ? zB1 : 0.2f * zB1));
        rs0 += wA0 + wB0; rs1 += wA1 + wB1;
        a00 += wA0 * vA00 + wB0 * vB00;
        a01 += wA0 * vA01 + wB0 * vB01;
        a10 += wA1 * vA10 + wB1 * vB10;
        a11 += wA1 * vA11 + wB1 * vB11;
    }
    if (idx < b1) {
        int2 eg = csr[idx];
        unsigned ey = (unsigned)eg.y;
        int r1 = (int)(ey & 0xFFFFu);
        unsigned r2 = ey >> 16;
        const __hip_bfloat16* rA = pB + (size_t)eg.x * PBS;
        float2 sA = *(const float2*)(rA + 200);
        float v00 = toF(rA[k0]), v10 = toF(rA[100 + k0]);
        float v01 = 0.f, v11 = 0.f;
        if (k1ok) { v01 = toF(rA[k1]); v11 = toF(rA[100 + k1]); }
        const float* q0 = rpf2 + (size_t)r1 * 100;
        const float* q1 = rph1 + (size_t)r1 * 100;
        float sr0 = srel2[r1], sr1 = srel2[R_ + r1];
        v00 += q0[k0]; v10 += q1[k0];
        if (k1ok) { v01 += q0[k1]; v11 += q1[k1]; }
        if (r2 != 0xFFFFu) {
            const float* t0 = rpf2 + (size_t)r2 * 100;
            const float* t1 = rph1 + (size_t)r2 * 100;
            sr0 += srel2[(int)r2]; sr1 += srel2[R_ + (int)r2];
            v00 += t0[k0]; v10 += t1[k0];
            if (k1ok) { v01 += t0[k1]; v11 += t1[k1]; }
        }
        float z0 = s1h0 + sA.x + sr0, z1 = s1h1 + sA.y + sr1;
        float w0 = expf(-(z0 > 0.f ? z0 : 0.2f * z0));
        float w1 = expf(-(z1 > 0.f ? z1 : 0.2f * z1));
        rs0 += w0; rs1 += w1;
        a00 += w0 * v00; a01 += w0 * v01;
        a10 += w1 * v10; a11 += w1 * v11;
    }

    float i0 = rs0 > 0.f ? 1.f / rs0 : 0.f;
    float i1 = rs1 > 0.f ? 1.f / rs1 : 0.f;
    __hip_bfloat16* xr = x1 + (size_t)n * KP;
    float hp;
    hp = rs0 > 0.f ? toF(xr[k0]) + a00 * i0 : 0.f;
    xr[k0] = __float2bfloat16(hp > 0.f ? hp : expf(hp) - 1.f);
    hp = rs1 > 0.f ? toF(xr[100 + k0]) + a10 * i1 : 0.f;
    xr[100 + k0] = __float2bfloat16(hp > 0.f ? hp : expf(hp) - 1.f);
    if (k1ok) {
        hp = rs0 > 0.f ? toF(xr[k1]) + a01 * i0 : 0.f;
        xr[k1] = __float2bfloat16(hp > 0.f ? hp : expf(hp) - 1.f);
        hp = rs1 > 0.f ? toF(xr[100 + k1]) + a11 * i1 : 0.f;
        xr[100 + k1] = __float2bfloat16(hp > 0.f ? hp : expf(hp) - 1.f);
    }
}

// -------- layer-2 gather, wave per dst; 2-edge unrolled; fused combine -----
__global__ __launch_bounds__(256)
void gather_l2_k(const int* __restrict__ start, const int2* __restrict__ csr,
                 const float* __restrict__ s1,
                 const float* __restrict__ srel,
                 const __hip_bfloat16* __restrict__ x1A2,  // [N][PBS] + s2 in pad
                 const float* __restrict__ rpf,            // [R][200]
                 const float* __restrict__ maskf,
                 float* __restrict__ outent, int N)        // [N][200], holds x1A1
{
    int n = (blockIdx.x * blockDim.x + threadIdx.x) >> 6;
    int lane = threadIdx.x & 63;
    if (n >= N) return;
    int b0 = start[n], b1 = start[n + 1];
    float s1n = s1[n];
    float rs = 0.f;
    float a[4] = {0.f, 0.f, 0.f, 0.f};

    int idx = b0;
    for (; idx + 1 < b1; idx += 2) {
        int2 eA = csr[idx], eB = csr[idx + 1];
        unsigned eyA = (unsigned)eA.y, eyB = (unsigned)eB.y;
        int r1A = (int)(eyA & 0xFFFFu), r1B = (int)(eyB & 0xFFFFu);
        unsigned r2A = eyA >> 16, r2B = eyB >> 16;
        const __hip_bfloat16* xA = x1A2 + (size_t)eA.x * PBS;
        const __hip_bfloat16* xB = x1A2 + (size_t)eB.x * PBS;
        float s2A = *(const float*)(xA + 200);
        float s2B = *(const float*)(xB + 200);
        float srA = srel[r1A] + (r2A != 0xFFFFu ? srel[(int)r2A] : 0.f);
        float srB = srel[r1B] + (r2B != 0xFFFFu ? srel[(int)r2B] : 0.f);
        const float* qA1 = rpf + (size_t)r1A * 200;
        const float* qB1 = rpf + (size_t)r1B * 200;
        const float* qA2 = (r2A != 0xFFFFu) ? (rpf + (size_t)r2A * 200) : nullptr;
        const float* qB2 = (r2B != 0xFFFFu) ? (rpf + (size_t)r2B * 200) : nullptr;
        float zA = s1n + s2A + srA, zB = s1n + s2B + srB;
        float wA = expf(-(zA > 0.f ? zA : 0.2f * zA));
        float wB = expf(-(zB > 0.f ? zB : 0.2f * zB));
        rs += wA + wB;
#pragma unroll
        for (int s = 0; s < 4; s++) {
            int k = lane + 64 * s;
            if (k < 200) {
                float vA = toF(xA[k]) + qA1[k] + (qA2 ? qA2[k] : 0.f);
                float vB = toF(xB[k]) + qB1[k] + (qB2 ? qB2[k] : 0.f);
                a[s] += wA * vA + wB * vB;
            }
        }
    }
    if (idx < b1) {
        int2 eg = csr[idx];
        unsigned ey = (unsigned)eg.y;
        int r1 = (int)(ey & 0xFFFFu);
        unsigned r2 = ey >> 16;
        const __hip_bfloat16* xs = x1A2 + (size_t)eg.x * PBS;
        float s2v = *(const float*)(xs + 200);
        float sr = srel[r1] + (r2 != 0xFFFFu ? srel[(int)r2] : 0.f);
        float z = s1n + s2v + sr;
        float w = expf(-(z > 0.f ? z : 0.2f * z));
        rs += w;
        const float* q1 = rpf + (size_t)r1 * 200;
        const float* q2 = (r2 != 0xFFFFu) ? (rpf + (size_t)r2 * 200) : nullptr;
#pragma unroll
        for (int s = 0; s < 4; s++) {
            int k = lane + 64 * s;
            if (k < 200) {
                float v = toF(xs[k]) + q1[k] + (q2 ? q2[k] : 0.f);
                a[s] += w * v;
            }
        }
    }

    float inv = rs > 0.f ? 1.f / rs : 0.f;
    float mk = maskf[n];
    float* orow = outent + (size_t)n * 200;
#pragma unroll
    for (int s = 0; s < 4; s++) {
        int k = lane + 64 * s;
        if (k < 200) {
            float hp = rs > 0.f ? orow[k] + a[s] * inv : 0.f;
            float e = hp > 0.f ? hp : expf(hp) - 1.f;
            orow[k] = mk * e;
        }
    }
}

__global__ void scatter_mask_k(const int* __restrict__ batch, int NB,
                               float* __restrict__ masko)
{
    int i = blockIdx.x * blockDim.x + threadIdx.x;
    if (i >= NB) return;
    masko[batch[i]] = 1.0f;
}

extern "C" void kernel_launch(void* const* d_in, const int* in_sizes, int n_in,
                              void* d_out, int out_size, void* d_ws, size_t ws_size,
                              hipStream_t stream)
{
    const float* ent      = (const float*)d_in[0];
    const float* rel      = (const float*)d_in[1];
    const float* W_ent    = (const float*)d_in[2];
    const float* W_gat    = (const float*)d_in[3];
    const float* a_heads  = (const float*)d_in[4];
    const float* a2_heads = (const float*)d_in[5];
    const float* a_out    = (const float*)d_in[6];
    const float* a2_out   = (const float*)d_in[7];
    const int* batch = (const int*)d_in[8];
    const int* el    = (const int*)d_in[9];
    const int* etype = (const int*)d_in[10];
    const int* tin   = (const int*)d_in[11];

    const int N   = in_sizes[0] / DD;   // 50000
    const int R   = in_sizes[1] / DD;   // 500
    const int NB  = in_sizes[8];        // 20000
    const int E   = in_sizes[9] / 2;    // 150000
    const int ENH = in_sizes[11] / 4;   // 30000
    const int Etot = E + ENH;

    // ---- workspace (~48 MB) ----
    char* ws = (char*)d_ws;
    size_t off = 0;
    auto take = [&](size_t bytes) { size_t o = off; off += (bytes + 255) & ~(size_t)255; return o; };
    size_t o_R1   = take((size_t)N * KP * 2);     // x1 bf16 [N][KP]
    size_t o_R2   = take((size_t)N * PBS * 2);    // pB [N][PBS]; later x1A2 [N][PBS]
    size_t o_rpf  = take((size_t)2 * R * 100 * 4);// rpf2 [2][R][100] / layer2 rpf [R][200]
    size_t o_bt1  = take((size_t)400 * KP * 2);
    size_t o_bt2  = take((size_t)400 * KP * 2);
    size_t o_btf  = take((size_t)208 * KP * 2);
    size_t o_nsc  = take((size_t)N * 4);
    size_t o_s1   = take((size_t)2 * N * 4);      // also aliased by cnt during CSR build
    size_t o_srel = take((size_t)2 * R * 4);
    size_t o_csr  = take((size_t)Etot * 8);
    size_t o_str  = take((size_t)(N + 1) * 4);
    size_t o_aux  = take((size_t)64 * 4);

    __hip_bfloat16* x1   = (__hip_bfloat16*)(ws + o_R1);
    __hip_bfloat16* pB   = (__hip_bfloat16*)(ws + o_R2); // [N][PBS]
    __hip_bfloat16* x1A2 = (__hip_bfloat16*)(ws + o_R2); // [N][PBS] after pB dead
    float* rpf2   = (float*)(ws + o_rpf);
    __hip_bfloat16* bt1 = (__hip_bfloat16*)(ws + o_bt1);
    __hip_bfloat16* bt2 = (__hip_bfloat16*)(ws + o_bt2);
    __hip_bfloat16* btf = (__hip_bfloat16*)(ws + o_btf);
    float* nscale = (float*)(ws + o_nsc);
    float* s1     = (float*)(ws + o_s1);
    float* srel2  = (float*)(ws + o_srel);
    int2*  csr    = (int2*)(ws + o_csr);
    int*   cnt    = (int*)(ws + o_s1);   // CSR-build scratch; dead before l1_both_k writes s1
    int*   startA = (int*)(ws + o_str);
    int*   aux    = (int*)(ws + o_aux);

    float* out       = (float*)d_out;
    float* out_ent   = out;                                     // [N,200]
    float* out_rel_o = out + (size_t)N * OD;                    // [500,200]
    float* out_mask  = out + (size_t)N * OD + (size_t)R * OD;   // [N]

    const int nblk = cdiv(N, 64);
    const int nbScan = cdiv(N, 1024);

    // A. prep: norms, B panels, x1 pad; out_rel GEMM
    rownorm_inv_k<<<cdiv(N, 4), 256, 0, stream>>>(ent, nscale, N, DD);
    prep_bt_l1<<<400, 256, 0, stream>>>(a_heads, bt1);
    prep_bt_l2<<<400, 256, 0, stream>>>(a_out, bt2);
    prep_bt_fin<<<208, 256, 0, stream>>>(W_ent, btf);
    hipMemsetAsync(x1, 0, (size_t)N * KP * 2, stream);
    gemm_mfma_k<false, float, float><<<dim3(cdiv(OD, 64), cdiv(R, 64)), 256, 0, stream>>>(
        rel, DD, nullptr, W_gat, OD, 0, out_rel_o, OD, R, OD, DD);

    // A2. CSR build (dst-grouped edge lists)
    hipMemsetAsync(cnt, 0, (size_t)N * 4, stream);
    hist_k<<<cdiv(Etot, 256), 256, 0, stream>>>(el, E, etype, tin, Etot, cnt);
    scan1_k<<<nbScan, 1024, 0, stream>>>(cnt, startA, aux, N);
    scan2_k<<<1, 64, 0, stream>>>(aux, nbScan);
    scan3_k<<<nbScan, 1024, 0, stream>>>(startA, aux, N, Etot);
    hipMemsetAsync(cnt, 0, (size_t)N * 4, stream);
    fill_k<<<cdiv(Etot, 256), 256, 0, stream>>>(el, E, etype, tin, Etot, startA, cnt, csr);

    // B. layer-1 projections (both heads) + rel projections + gather
    l1_both_k<<<nblk, 256, 0, stream>>>(ent, nscale, bt1, a2_heads, x1, pB, s1, N);
    for (int h = 0; h < 2; h++) {
        const float* ah  = a_heads + (size_t)h * NHID * 600;
        const float* a2h = a2_heads + (size_t)h * NHID;
        gemm_mfma_k<true, float, float><<<dim3(cdiv(NHID, 64), cdiv(R, 64)), 256, 0, stream>>>(
            rel, DD, nullptr, ah, 600, 400, rpf2 + (size_t)h * R * NHID, NHID, R, NHID, DD);
        rowdot_k<float><<<cdiv(R, 4), 256, 0, stream>>>(
            rpf2 + (size_t)h * R * NHID, NHID, 0, a2h, srel2 + (size_t)h * R, R, NHID);
    }
    gather_l1_k<<<cdiv(N, 4), 256, 0, stream>>>(
        startA, csr, s1, srel2, R, pB, rpf2, x1, N);
    // pB dead; R2 becomes x1A2.

    // C. layer-2 projection + rel side
    l2_proj_k<<<nblk, 256, 0, stream>>>(x1, bt2, a2_out, out_ent, x1A2, s1, N);
    gemm_mfma_k<true, float, float><<<dim3(cdiv(OD, 64), cdiv(R, 64)), 256, 0, stream>>>(
        out_rel_o, OD, nullptr, a_out, 600, 400, rpf2, OD, R, OD, OD);
    rowdot_k<float><<<cdiv(R, 4), 256, 0, stream>>>(rpf2, OD, 0, a2_out, srel2, R, OD);

    // D. mask; layer-2 gather (fused combine, single 200-wide pass)
    hipMemsetAsync(out_mask, 0, (size_t)N * 4, stream);
    scatter_mask_k<<<cdiv(NB, 256), 256, 0, stream>>>(batch, NB, out_mask);
    gather_l2_k<<<cdiv(N, 4), 256, 0, stream>>>(
        startA, csr, s1, srel2, x1A2, rpf2, out_mask, out_ent, N);

    // E. fused final GEMM + l2norm
    final_mfma_k<<<nblk, 256, 0, stream>>>(ent, nscale, btf, out_ent, N);
}

// Round 2
// 521.268 us; speedup vs baseline: 1.1752x; 1.1132x over previous
//
#include <hip/hip_runtime.h>
#include <hip/hip_bf16.h>
#include <math.h>

// SpKBGAT: N=50000, D=200, R=500, NHID=100, H=2, OD=200, E=150000, ENH=30000.
// R10: the three tall-skinny MFMA kernels (l1_both, l2_proj, final) were
// latency-bound on per-tile global B loads from L2 (MfmaUtil 4%, VALU 8%).
// Fix: LDS-stage the Bt k-chunk per block ([rows][40] bf16, 80B stride ->
// bank-balanced ds_read_b128), prefetch next chunk into regs under the MFMAs.
#define DD   200
#define NHID 100
#define OD   200
#define KP   224   // padded K (7 chunks of 32)
#define PBS  224   // padded row stride (bf16) for pB / x1A2: 448 B
                   // layout: [0..99]=h0, [100..199]=h1, bytes 400..407 = s2
#define LDSW 40    // LDS row stride in shorts (80 B): 16B-aligned, bank-balanced

typedef __attribute__((ext_vector_type(8))) short short8;
typedef __attribute__((ext_vector_type(4))) float f32x4;

static inline int cdiv(int a, int b) { return (a + b - 1) / b; }

__device__ inline float toF(float x) { return x; }
__device__ inline float toF(__hip_bfloat16 x) { return __bfloat162float(x); }
__device__ inline void storeC(float v, float* p) { *p = v; }
__device__ inline void storeC(float v, __hip_bfloat16* p) { *p = __float2bfloat16(v); }
__device__ inline short bf16s(float f) {
    __hip_bfloat16 h = __float2bfloat16(f);
    short s; __builtin_memcpy(&s, &h, 2); return s;
}

// -------- per-row inverse L2 norm (f32), wave per row --------
__global__ __launch_bounds__(256)
void rownorm_inv_k(const float* __restrict__ in, float* __restrict__ sc, int M, int Dd)
{
    int wave = (blockIdx.x * blockDim.x + threadIdx.x) >> 6;
    int lane = threadIdx.x & 63;
    if (wave >= M) return;
    float ss = 0.f;
    for (int k = lane; k < Dd; k += 64) {
        float x = in[(size_t)wave * Dd + k];
        ss += x * x;
    }
    for (int o = 32; o > 0; o >>= 1) ss += __shfl_down(ss, o);
    if (lane == 0) sc[wave] = 1.f / fmaxf(sqrtf(ss), 1e-12f);
}

// -------- B-panel prep: bf16 [col][KP], zero-padded --------
__global__ void prep_bt_l1(const float* __restrict__ ah, __hip_bfloat16* __restrict__ Bt)
{
    int c = blockIdx.x, k = threadIdx.x;
    if (k >= KP) return;
    int seg = c / 100, idx = c - seg * 100;
    int h = seg & 1, off = (seg >> 1) * 200;
    float v = (k < 200) ? ah[(size_t)(h * 100 + idx) * 600 + off + k] : 0.f;
    Bt[(size_t)c * KP + k] = __float2bfloat16(v);
}
__global__ void prep_bt_l2(const float* __restrict__ ao, __hip_bfloat16* __restrict__ Bt)
{
    int c = blockIdx.x, k = threadIdx.x;
    if (k >= KP) return;
    int row = (c < 200) ? c : c - 200;
    int off = (c < 200) ? 0 : 200;
    float v = (k < 200) ? ao[(size_t)row * 600 + off + k] : 0.f;
    Bt[(size_t)c * KP + k] = __float2bfloat16(v);
}
__global__ void prep_bt_fin(const float* __restrict__ W, __hip_bfloat16* __restrict__ Bt)
{
    int c = blockIdx.x, k = threadIdx.x;
    if (k >= KP) return;
    float v = (c < 200 && k < 200) ? W[(size_t)k * 200 + c] : 0.f;
    Bt[(size_t)c * KP + k] = __float2bfloat16(v);
}

// -------- layer-1 fused (both heads): 25 tiles = xa1_h0|xa1_h1|xa2_h0|xa2_h1
__global__ __launch_bounds__(256)
void l1_both_k(const float* __restrict__ ent, const float* __restrict__ nscale,
               const __hip_bfloat16* __restrict__ Bt,  // [400][KP]
               const float* __restrict__ a2h,          // [2][100]
               __hip_bfloat16* __restrict__ x1,        // [N][KP] (cols 0-199)
               __hip_bfloat16* __restrict__ pB,        // [N][PBS] + s2 in pad
               float* __restrict__ s1,                 // [2][N]
               int M)
{
    __shared__ __align__(16) __hip_bfloat16 Bs[400 * LDSW];  // 32 KB
    int tid = threadIdx.x, wave = tid >> 6, lane = tid & 63;
    int quad = lane >> 4, l16 = lane & 15;
    int m0 = blockIdx.x * 64;
    int arow = m0 + wave * 16 + l16;
    bool rok = arow < M;
    float nsc = rok ? nscale[arow] : 0.f;
    const float* arp = ent + (size_t)arow * DD;

    f32x4 acc[25];
#pragma unroll
    for (int t = 0; t < 25; t++) acc[t] = (f32x4){0.f, 0.f, 0.f, 0.f};

    // 400 rows x 32 cols / chunk = 1600 16B-pieces; 256 threads x 7
    short8 stg[7];
#pragma unroll
    for (int i = 0; i < 7; i++) {
        int idx = tid + i * 256;
        if (idx < 1600) {
            int r = idx >> 2, c8 = idx & 3;
            stg[i] = *(const short8*)(Bt + (size_t)r * KP + c8 * 8);
        }
    }

    for (int ch = 0; ch < 7; ch++) {
#pragma unroll
        for (int i = 0; i < 7; i++) {
            int idx = tid + i * 256;
            if (idx < 1600) {
                int r = idx >> 2, c8 = idx & 3;
                *(short8*)(Bs + r * LDSW + c8 * 8) = stg[i];
            }
        }
        __syncthreads();
        if (ch < 6) {
            int kb2 = (ch + 1) * 32;
#pragma unroll
            for (int i = 0; i < 7; i++) {
                int idx = tid + i * 256;
                if (idx < 1600) {
                    int r = idx >> 2, c8 = idx & 3;
                    stg[i] = *(const short8*)(Bt + (size_t)r * KP + kb2 + c8 * 8);
                }
            }
        }
        int kb = ch * 32 + quad * 8;
        float av[8];
        if (rok && kb + 8 <= DD) {
            const float4* p = (const float4*)(arp + kb);
            float4 u0 = p[0], u1 = p[1];
            av[0] = u0.x; av[1] = u0.y; av[2] = u0.z; av[3] = u0.w;
            av[4] = u1.x; av[5] = u1.y; av[6] = u1.z; av[7] = u1.w;
        } else {
#pragma unroll
            for (int j = 0; j < 8; j++) av[j] = (rok && kb + j < DD) ? arp[kb + j] : 0.f;
        }
        short8 a;
#pragma unroll
        for (int j = 0; j < 8; j++) a[j] = bf16s(av[j] * nsc);
        const __hip_bfloat16* bp = Bs + (size_t)l16 * LDSW + quad * 8;
#pragma unroll
        for (int t = 0; t < 25; t++) {
            short8 b = *(const short8*)(bp + (size_t)t * 16 * LDSW);
            acc[t] = __builtin_amdgcn_mfma_f32_16x16x32_bf16(a, b, acc[t], 0, 0, 0);
        }
        __syncthreads();
    }

    int orow = m0 + wave * 16 + quad * 4;
    float d0[4] = {0,0,0,0}, d1[4] = {0,0,0,0}, d2[4] = {0,0,0,0}, d3[4] = {0,0,0,0};
#pragma unroll
    for (int t = 0; t < 25; t++) {
        int c = t * 16 + l16;
        int seg = c / 100, idx = c - seg * 100;
        float w = a2h[(seg & 1) * 100 + idx];
#pragma unroll
        for (int i = 0; i < 4; i++) {
            float v = acc[t][i];
            float vw = v * w;
            if (seg == 0) d0[i] += vw;
            else if (seg == 1) d1[i] += vw;
            else if (seg == 2) d2[i] += vw;
            else d3[i] += vw;
            int gm = orow + i;
            if (gm < M) {
                if (seg < 2) x1[(size_t)gm * KP + c] = __float2bfloat16(v);
                else pB[(size_t)gm * PBS + (seg - 2) * 100 + idx] = __float2bfloat16(v);
            }
        }
    }
#pragma unroll
    for (int msk = 1; msk < 16; msk <<= 1)
#pragma unroll
        for (int i = 0; i < 4; i++) {
            d0[i] += __shfl_xor(d0[i], msk);
            d1[i] += __shfl_xor(d1[i], msk);
            d2[i] += __shfl_xor(d2[i], msk);
            d3[i] += __shfl_xor(d3[i], msk);
        }
    if (l16 == 0)
#pragma unroll
        for (int i = 0; i < 4; i++) {
            int gm = orow + i;
            if (gm < M) {
                s1[gm] = d0[i]; s1[M + gm] = d1[i];
                float2 sv; sv.x = d2[i]; sv.y = d3[i];
                *(float2*)((char*)pB + (size_t)gm * (PBS * 2) + 400) = sv;
            }
        }
}

// -------- layer-2 fused: 25 tiles = x1A1 (f32 -> out_ent) | x1A2 (bf16) ----
__global__ __launch_bounds__(256)
void l2_proj_k(const __hip_bfloat16* __restrict__ x1,  // [N][KP]
               const __hip_bfloat16* __restrict__ Bt,  // [400][KP]
               const float* __restrict__ a2o,          // [200]
               float* __restrict__ x1A1,               // [N][200] (out_ent)
               __hip_bfloat16* __restrict__ x1A2,      // [N][PBS], s2 in pad
               float* __restrict__ s1, int M)
{
    __shared__ __align__(16) __hip_bfloat16 Bs[400 * LDSW];  // 32 KB
    int tid = threadIdx.x, wave = tid >> 6, lane = tid & 63;
    int quad = lane >> 4, l16 = lane & 15;
    int m0 = blockIdx.x * 64;
    int arow = m0 + wave * 16 + l16;
    bool rok = arow < M;
    const __hip_bfloat16* arp = x1 + (size_t)arow * KP;

    f32x4 acc[25];
#pragma unroll
    for (int t = 0; t < 25; t++) acc[t] = (f32x4){0.f, 0.f, 0.f, 0.f};

    short8 stg[7];
#pragma unroll
    for (int i = 0; i < 7; i++) {
        int idx = tid + i * 256;
        if (idx < 1600) {
            int r = idx >> 2, c8 = idx & 3;
            stg[i] = *(const short8*)(Bt + (size_t)r * KP + c8 * 8);
        }
    }

    for (int ch = 0; ch < 7; ch++) {
#pragma unroll
        for (int i = 0; i < 7; i++) {
            int idx = tid + i * 256;
            if (idx < 1600) {
                int r = idx >> 2, c8 = idx & 3;
                *(short8*)(Bs + r * LDSW + c8 * 8) = stg[i];
            }
        }
        __syncthreads();
        if (ch < 6) {
            int kb2 = (ch + 1) * 32;
#pragma unroll
            for (int i = 0; i < 7; i++) {
                int idx = tid + i * 256;
                if (idx < 1600) {
                    int r = idx >> 2, c8 = idx & 3;
                    stg[i] = *(const short8*)(Bt + (size_t)r * KP + kb2 + c8 * 8);
                }
            }
        }
        int kb = ch * 32 + quad * 8;
        short8 a = (short8){0,0,0,0,0,0,0,0};
        if (rok) a = *(const short8*)(arp + kb);
        const __hip_bfloat16* bp = Bs + (size_t)l16 * LDSW + quad * 8;
#pragma unroll
        for (int t = 0; t < 25; t++) {
            short8 b = *(const short8*)(bp + (size_t)t * 16 * LDSW);
            acc[t] = __builtin_amdgcn_mfma_f32_16x16x32_bf16(a, b, acc[t], 0, 0, 0);
        }
        __syncthreads();
    }

    int orow = m0 + wave * 16 + quad * 4;
    float dA[4] = {0,0,0,0}, dB[4] = {0,0,0,0};
#pragma unroll
    for (int t = 0; t < 25; t++) {
        int c = t * 16 + l16;
        bool first = c < 200;
        int cc = first ? c : c - 200;
        float w = a2o[cc];
#pragma unroll
        for (int i = 0; i < 4; i++) {
            float v = acc[t][i];
            int gm = orow + i;
            if (first) {
                dA[i] += v * w;
                if (gm < M) x1A1[(size_t)gm * OD + c] = v;
            } else {
                dB[i] += v * w;
                if (gm < M) x1A2[(size_t)gm * PBS + cc] = __float2bfloat16(v);
            }
        }
    }
#pragma unroll
    for (int msk = 1; msk < 16; msk <<= 1)
#pragma unroll
        for (int i = 0; i < 4; i++) {
            dA[i] += __shfl_xor(dA[i], msk);
            dB[i] += __shfl_xor(dB[i], msk);
        }
    if (l16 == 0)
#pragma unroll
        for (int i = 0; i < 4; i++) {
            int gm = orow + i;
            if (gm < M) {
                s1[gm] = dA[i];
                *(float*)((char*)x1A2 + (size_t)gm * (PBS * 2) + 400) = dB[i];
            }
        }
}

// -------- final: out_ent = l2norm(out_ent + (ent*nscale) @ W_ent) ---------
__global__ __launch_bounds__(256)
void final_mfma_k(const float* __restrict__ ent, const float* __restrict__ nscale,
                  const __hip_bfloat16* __restrict__ Bt,  // [208][KP]
                  float* __restrict__ outent, int M)
{
    __shared__ __align__(16) __hip_bfloat16 Bs[208 * LDSW];  // 16.6 KB
    int tid = threadIdx.x, wave = tid >> 6, lane = tid & 63;
    int quad = lane >> 4, l16 = lane & 15;
    int m0 = blockIdx.x * 64;
    int arow = m0 + wave * 16 + l16;
    bool rok = arow < M;
    float nsc = rok ? nscale[arow] : 0.f;
    const float* arp = ent + (size_t)arow * DD;

    f32x4 acc[13];
#pragma unroll
    for (int t = 0; t < 13; t++) acc[t] = (f32x4){0.f, 0.f, 0.f, 0.f};

    // 208 rows x 32 cols = 832 16B-pieces; 256 threads x 4
    short8 stg[4];
#pragma unroll
    for (int i = 0; i < 4; i++) {
        int idx = tid + i * 256;
        if (idx < 832) {
            int r = idx >> 2, c8 = idx & 3;
            stg[i] = *(const short8*)(Bt + (size_t)r * KP + c8 * 8);
        }
    }

    for (int ch = 0; ch < 7; ch++) {
#pragma unroll
        for (int i = 0; i < 4; i++) {
            int idx = tid + i * 256;
            if (idx < 832) {
                int r = idx >> 2, c8 = idx & 3;
                *(short8*)(Bs + r * LDSW + c8 * 8) = stg[i];
            }
        }
        __syncthreads();
        if (ch < 6) {
            int kb2 = (ch + 1) * 32;
#pragma unroll
            for (int i = 0; i < 4; i++) {
                int idx = tid + i * 256;
                if (idx < 832) {
                    int r = idx >> 2, c8 = idx & 3;
                    stg[i] = *(const short8*)(Bt + (size_t)r * KP + kb2 + c8 * 8);
                }
            }
        }
        int kb = ch * 32 + quad * 8;
        float av[8];
        if (rok && kb + 8 <= DD) {
            const float4* p = (const float4*)(arp + kb);
            float4 u0 = p[0], u1 = p[1];
            av[0] = u0.x; av[1] = u0.y; av[2] = u0.z; av[3] = u0.w;
            av[4] = u1.x; av[5] = u1.y; av[6] = u1.z; av[7] = u1.w;
        } else {
#pragma unroll
            for (int j = 0; j < 8; j++) av[j] = (rok && kb + j < DD) ? arp[kb + j] : 0.f;
        }
        short8 a;
#pragma unroll
        for (int j = 0; j < 8; j++) a[j] = bf16s(av[j] * nsc);
        const __hip_bfloat16* bp = Bs + (size_t)l16 * LDSW + quad * 8;
#pragma unroll
        for (int t = 0; t < 13; t++) {
            short8 b = *(const short8*)(bp + (size_t)t * 16 * LDSW);
            acc[t] = __builtin_amdgcn_mfma_f32_16x16x32_bf16(a, b, acc[t], 0, 0, 0);
        }
        __syncthreads();
    }

    int orow = m0 + wave * 16 + quad * 4;
    float ss[4] = {0.f, 0.f, 0.f, 0.f};
#pragma unroll
    for (int t = 0; t < 13; t++) {
        int gn = t * 16 + l16;
#pragma unroll
        for (int i = 0; i < 4; i++) {
            int gm = orow + i;
            float v = 0.f;
            if (gn < OD && gm < M) v = acc[t][i] + outent[(size_t)gm * OD + gn];
            acc[t][i] = v;
            ss[i] += v * v;
        }
    }
#pragma unroll
    for (int msk = 1; msk < 16; msk <<= 1)
#pragma unroll
        for (int i = 0; i < 4; i++) ss[i] += __shfl_xor(ss[i], msk);
    float scl[4];
#pragma unroll
    for (int i = 0; i < 4; i++) scl[i] = 1.f / fmaxf(sqrtf(ss[i]), 1e-12f);
#pragma unroll
    for (int t = 0; t < 13; t++) {
        int gn = t * 16 + l16;
        if (gn >= OD) continue;
#pragma unroll
        for (int i = 0; i < 4; i++) {
            int gm = orow + i;
            if (gm < M) outent[(size_t)gm * OD + gn] = acc[t][i] * scl[i];
        }
    }
}

// -------- generic MFMA GEMM (small R-sized matmuls) --------
#define KPAD 48
template<bool BTr, typename AT, typename CT>
__global__ __launch_bounds__(256)
void gemm_mfma_k(const AT* __restrict__ A, int lda, const float* __restrict__ ascale,
                 const float* __restrict__ B, int ldb, int colOff,
                 CT* __restrict__ C, int ldc, int M, int Nc, int K)
{
    __shared__ __align__(16) __hip_bfloat16 As[64][KPAD];
    __shared__ __align__(16) __hip_bfloat16 Bs[64][KPAD];
    int tid  = threadIdx.x;
    int wave = tid >> 6, lane = tid & 63;
    int quad = lane >> 4, l16 = lane & 15;
    int n0 = blockIdx.x * 64, m0 = blockIdx.y * 64;
    f32x4 acc[4];
#pragma unroll
    for (int t = 0; t < 4; t++) acc[t] = (f32x4){0.f, 0.f, 0.f, 0.f};

    for (int k0 = 0; k0 < K; k0 += 32) {
        {
            int m = tid >> 2, kc = (tid & 3) * 8;
            int gm = m0 + m;
            float scale = (ascale && gm < M) ? ascale[gm] : 1.f;
#pragma unroll
            for (int j = 0; j < 8; j++) {
                int gk = k0 + kc + j;
                float v = 0.f;
                if (gm < M && gk < K) v = toF(A[(size_t)gm * lda + gk]) * scale;
                As[m][kc + j] = __float2bfloat16(v);
            }
        }
        if (BTr) {
            int n = tid >> 2, kc = (tid & 3) * 8;
            int gn = n0 + n;
#pragma unroll
            for (int j = 0; j < 8; j++) {
                int gk = k0 + kc + j;
                float v = 0.f;
                if (gn < Nc && gk < K) v = B[(size_t)gn * ldb + colOff + gk];
                Bs[n][kc + j] = __float2bfloat16(v);
            }
        } else {
            int n = tid & 63, kq = tid >> 6;
            int gn = n0 + n;
#pragma unroll
            for (int j = 0; j < 8; j++) {
                int gk = k0 + kq * 8 + j;
                float v = 0.f;
                if (gn < Nc && gk < K) v = B[(size_t)gk * ldb + gn];
                Bs[n][kq * 8 + j] = __float2bfloat16(v);
            }
        }
        __syncthreads();
        short8 a = *(const short8*)&As[wave * 16 + l16][quad * 8];
#pragma unroll
        for (int t = 0; t < 4; t++) {
            short8 b = *(const short8*)&Bs[t * 16 + l16][quad * 8];
            acc[t] = __builtin_amdgcn_mfma_f32_16x16x32_bf16(a, b, acc[t], 0, 0, 0);
        }
        __syncthreads();
    }
#pragma unroll
    for (int t = 0; t < 4; t++) {
        int gn = n0 + t * 16 + l16;
        if (gn >= Nc) continue;
#pragma unroll
        for (int i = 0; i < 4; i++) {
            int gm = m0 + wave * 16 + quad * 4 + i;
            if (gm < M) storeC(acc[t][i], &C[(size_t)gm * ldc + gn]);
        }
    }
}

// -------- row-dot (srel) --------
template<typename T>
__global__ __launch_bounds__(256)
void rowdot_k(const T* __restrict__ mat, int ld, int coff,
              const float* __restrict__ vec,
              float* __restrict__ outp, int M, int Dd)
{
    int wave = (blockIdx.x * blockDim.x + threadIdx.x) >> 6;
    int lane = threadIdx.x & 63;
    if (wave >= M) return;
    float s = 0.f;
    for (int k = lane; k < Dd; k += 64)
        s += toF(mat[(size_t)wave * ld + coff + k]) * vec[k];
    for (int o = 32; o > 0; o >>= 1) s += __shfl_down(s, o);
    if (lane == 0) outp[wave] = s;
}

// -------- CSR build --------
__device__ inline void decode_edge(const int* __restrict__ el, int E,
                                   const int* __restrict__ etype,
                                   const int* __restrict__ tin, int e,
                                   int& dst, int& src, int& r1, int& r2)
{
    if (e < E) { dst = el[e]; src = el[E + e]; r1 = etype[e]; r2 = -1; }
    else {
        int j = e - E;
        dst = tin[j * 4 + 3]; src = tin[j * 4 + 0];
        r1 = tin[j * 4 + 1];  r2 = tin[j * 4 + 2];
    }
}

__global__ void hist_k(const int* __restrict__ el, int E, const int* __restrict__ etype,
                       const int* __restrict__ tin, int Etot, int* __restrict__ cnt)
{
    int e = blockIdx.x * blockDim.x + threadIdx.x;
    if (e >= Etot) return;
    int dst, src, r1, r2; decode_edge(el, E, etype, tin, e, dst, src, r1, r2);
    atomicAdd(&cnt[dst], 1);
}

__global__ __launch_bounds__(1024)
void scan1_k(const int* __restrict__ cnt, int* __restrict__ start,
             int* __restrict__ aux, int n)
{
    __shared__ int tmp[1024];
    int i = blockIdx.x * 1024 + threadIdx.x;
    int v = (i < n) ? cnt[i] : 0;
    tmp[threadIdx.x] = v;
    __syncthreads();
    for (int o = 1; o < 1024; o <<= 1) {
        int t = (threadIdx.x >= (unsigned)o) ? tmp[threadIdx.x - o] : 0;
        __syncthreads();
        tmp[threadIdx.x] += t;
        __syncthreads();
    }
    if (i < n) start[i] = tmp[threadIdx.x] - v;
    if (threadIdx.x == 1023) aux[blockIdx.x] = tmp[1023];
}

__global__ void scan2_k(int* __restrict__ aux, int nb)
{
    if (threadIdx.x == 0 && blockIdx.x == 0) {
        int s = 0;
        for (int i = 0; i < nb; i++) { int v = aux[i]; aux[i] = s; s += v; }
    }
}

__global__ __launch_bounds__(1024)
void scan3_k(int* __restrict__ start, const int* __restrict__ aux, int n, int Etot)
{
    int i = blockIdx.x * 1024 + threadIdx.x;
    if (i < n) start[i] += aux[blockIdx.x];
    if (i == 0) start[n] = Etot;
}

// csr entry: .x = src, .y = r1 | (r2s<<16), r2s==0xFFFF means "no r2"
__global__ void fill_k(const int* __restrict__ el, int E, const int* __restrict__ etype,
                       const int* __restrict__ tin, int Etot,
                       const int* __restrict__ start, int* __restrict__ fill,
                       int2* __restrict__ csr)
{
    int e = blockIdx.x * blockDim.x + threadIdx.x;
    if (e >= Etot) return;
    int dst, src, r1, r2; decode_edge(el, E, etype, tin, e, dst, src, r1, r2);
    int p = start[dst] + atomicAdd(&fill[dst], 1);
    unsigned r2s = (r2 >= 0) ? (unsigned)r2 : 0xFFFFu;
    csr[p] = make_int2(src, (int)((r2s << 16) | (unsigned)r1));
}

// -------- layer-1 gather (both heads), wave per dst; 2-edge unrolled -------
__global__ __launch_bounds__(256)
void gather_l1_k(const int* __restrict__ start, const int2* __restrict__ csr,
                 const float* __restrict__ s1,                // [2][N] dst-side
                 const float* __restrict__ srel2, int R_,     // [2][R]
                 const __hip_bfloat16* __restrict__ pB,       // [N][PBS] + s2 in pad
                 const float* __restrict__ rpf2,              // [2][R][100]
                 __hip_bfloat16* __restrict__ x1, int N)      // [N][KP]
{
    int n = (blockIdx.x * blockDim.x + threadIdx.x) >> 6;
    int lane = threadIdx.x & 63;
    if (n >= N) return;
    int b0 = start[n], b1 = start[n + 1];
    float s1h0 = s1[n], s1h1 = s1[N + n];
    float rs0 = 0.f, rs1 = 0.f;
    float a00 = 0.f, a01 = 0.f, a10 = 0.f, a11 = 0.f;
    int k0 = lane, k1 = lane + 64;
    bool k1ok = k1 < 100;
    const float* rph1 = rpf2 + (size_t)R_ * 100;

    int idx = b0;
    for (; idx + 1 < b1; idx += 2) {
        int2 eA = csr[idx], eB = csr[idx + 1];
        unsigned eyA = (unsigned)eA.y, eyB = (unsigned)eB.y;
        int r1A = (int)(eyA & 0xFFFFu), r1B = (int)(eyB & 0xFFFFu);
        unsigned r2A = eyA >> 16, r2B = eyB >> 16;
        const __hip_bfloat16* rA = pB + (size_t)eA.x * PBS;
        const __hip_bfloat16* rB = pB + (size_t)eB.x * PBS;
        float2 sA = *(const float2*)(rA + 200);
        float2 sB = *(const float2*)(rB + 200);
        float vA00 = toF(rA[k0]), vA10 = toF(rA[100 + k0]);
        float vB00 = toF(rB[k0]), vB10 = toF(rB[100 + k0]);
        float vA01 = 0.f, vA11 = 0.f, vB01 = 0.f, vB11 = 0.f;
        if (k1ok) {
            vA01 = toF(rA[k1]); vA11 = toF(rA[100 + k1]);
            vB01 = toF(rB[k1]); vB11 = toF(rB[100 + k1]);
        }
        const float* qA0 = rpf2 + (size_t)r1A * 100;
        const float* qA1 = rph1 + (size_t)r1A * 100;
        const float* qB0 = rpf2 + (size_t)r1B * 100;
        const float* qB1 = rph1 + (size_t)r1B * 100;
        float srA0 = srel2[r1A], srA1 = srel2[R_ + r1A];
        float srB0 = srel2[r1B], srB1 = srel2[R_ + r1B];
        vA00 += qA0[k0]; vA10 += qA1[k0];
        vB00 += qB0[k0]; vB10 += qB1[k0];
        if (k1ok) {
            vA01 += qA0[k1]; vA11 += qA1[k1];
            vB01 += qB0[k1]; vB11 += qB1[k1];
        }
        if (r2A != 0xFFFFu) {
            const float* t0 = rpf2 + (size_t)r2A * 100;
            const float* t1 = rph1 + (size_t)r2A * 100;
            srA0 += srel2[(int)r2A]; srA1 += srel2[R_ + (int)r2A];
            vA00 += t0[k0]; vA10 += t1[k0];
            if (k1ok) { vA01 += t0[k1]; vA11 += t1[k1]; }
        }
        if (r2B != 0xFFFFu) {
            const float* t0 = rpf2 + (size_t)r2B * 100;
            const float* t1 = rph1 + (size_t)r2B * 100;
            srB0 += srel2[(int)r2B]; srB1 += srel2[R_ + (int)r2B];
            vB00 += t0[k0]; vB10 += t1[k0];
            if (k1ok) { vB01 += t0[k1]; vB11 += t1[k1]; }
        }
        float zA0 = s1h0 + sA.x + srA0, zA1 = s1h1 + sA.y + srA1;
        float zB0 = s1h0 + sB.x + srB0, zB1 = s1h1 + sB.y + srB1;
        float wA0 = expf(-(zA0 > 0.f ? zA0 : 0.2f * zA0));
        float wA1 = expf(-(zA1 > 0.f ? zA1 : 0.2f * zA1));
        float wB0 = expf(-(zB0 > 0.f ? zB0 : 0.2f * zB0));
        float wB1 = expf(-(zB1 > 0.f ? zB1 : 0.2f * zB1));
        rs0 += wA0 + wB0; rs1 += wA1 + wB1;
        a00 += wA0 * vA00 + wB0 * vB00;
        a01 += wA0 * vA01 + wB0 * vB01;
        a10 += wA1 * vA10 + wB1 * vB10;
        a11 += wA1 * vA11 + wB1 * vB11;
    }
    if (idx < b1) {
        int2 eg = csr[idx];
        unsigned ey = (unsigned)eg.y;
        int r1 = (int)(ey & 0xFFFFu);
        unsigned r2 = ey >> 16;
        const __hip_bfloat16* rA = pB + (size_t)eg.x * PBS;
        float2 sA = *(const float2*)(rA + 200);
        float v00 = toF(rA[k0]), v10 = toF(rA[100 + k0]);
        float v01 = 0.f, v11 = 0.f;
        if (k1ok) { v01 = toF(rA[k1]); v11 = toF(rA[100 + k1]); }
        const float* q0 = rpf2 + (size_t)r1 * 100;
        const float* q1 = rph1 + (size_t)r1 * 100;
        float sr0 = srel2[r1], sr1 = srel2[R_ + r1];
        v00 += q0[k0]; v10 += q1[k0];
        if (k1ok) { v01 += q0[k1]; v11 += q1[k1]; }
        if (r2 != 0xFFFFu) {
            const float* t0 = rpf2 + (size_t)r2 * 100;
            const float* t1 = rph1 + (size_t)r2 * 100;
            sr0 += srel2[(int)r2]; sr1 += srel2[R_ + (int)r2];
            v00 += t0[k0]; v10 += t1[k0];
            if (k1ok) { v01 += t0[k1]; v11 += t1[k1]; }
        }
        float z0 = s1h0 + sA.x + sr0, z1 = s1h1 + sA.y + sr1;
        float w0 = expf(-(z0 > 0.f ? z0 : 0.2f * z0));
        float w1 = expf(-(z1 > 0.f ? z1 : 0.2f * z1));
        rs0 += w0; rs1 += w1;
        a00 += w0 * v00; a01 += w0 * v01;
        a10 += w1 * v10; a11 += w1 * v11;
    }

    float i0 = rs0 > 0.f ? 1.f / rs0 : 0.f;
    float i1 = rs1 > 0.f ? 1.f / rs1 : 0.f;
    __hip_bfloat16* xr = x1 + (size_t)n * KP;
    float hp;
    hp = rs0 > 0.f ? toF(xr[k0]) + a00 * i0 : 0.f;
    xr[k0] = __float2bfloat16(hp > 0.f ? hp : expf(hp) - 1.f);
    hp = rs1 > 0.f ? toF(xr[100 + k0]) + a10 * i1 : 0.f;
    xr[100 + k0] = __float2bfloat16(hp > 0.f ? hp : expf(hp) - 1.f);
    if (k1ok) {
        hp = rs0 > 0.f ? toF(xr[k1]) + a01 * i0 : 0.f;
        xr[k1] = __float2bfloat16(hp > 0.f ? hp : expf(hp) - 1.f);
        hp = rs1 > 0.f ? toF(xr[100 + k1]) + a11 * i1 : 0.f;
        xr[100 + k1] = __float2bfloat16(hp > 0.f ? hp : expf(hp) - 1.f);
    }
}

// -------- layer-2 gather, wave per dst; 2-edge unrolled; fused combine -----
__global__ __launch_bounds__(256)
void gather_l2_k(const int* __restrict__ start, const int2* __restrict__ csr,
                 const float* __restrict__ s1,
                 const float* __restrict__ srel,
                 const __hip_bfloat16* __restrict__ x1A2,  // [N][PBS] + s2 in pad
                 const float* __restrict__ rpf,            // [R][200]
                 const float* __restrict__ maskf,
                 float* __restrict__ outent, int N)        // [N][200], holds x1A1
{
    int n = (blockIdx.x * blockDim.x + threadIdx.x) >> 6;
    int lane = threadIdx.x & 63;
    if (n >= N) return;
    int b0 = start[n], b1 = start[n + 1];
    float s1n = s1[n];
    float rs = 0.f;
    float a[4] = {0.f, 0.f, 0.f, 0.f};

    int idx = b0;
    for (; idx + 1 < b1; idx += 2) {
        int2 eA = csr[idx], eB = csr[idx + 1];
        unsigned eyA = (unsigned)eA.y, eyB = (unsigned)eB.y;
        int r1A = (int)(eyA & 0xFFFFu), r1B = (int)(eyB & 0xFFFFu);
        unsigned r2A = eyA >> 16, r2B = eyB >> 16;
        const __hip_bfloat16* xA = x1A2 + (size_t)eA.x * PBS;
        const __hip_bfloat16* xB = x1A2 + (size_t)eB.x * PBS;
        float s2A = *(const float*)(xA + 200);
        float s2B = *(const float*)(xB + 200);
        float srA = srel[r1A] + (r2A != 0xFFFFu ? srel[(int)r2A] : 0.f);
        float srB = srel[r1B] + (r2B != 0xFFFFu ? srel[(int)r2B] : 0.f);
        const float* qA1 = rpf + (size_t)r1A * 200;
        const float* qB1 = rpf + (size_t)r1B * 200;
        const float* qA2 = (r2A != 0xFFFFu) ? (rpf + (size_t)r2A * 200) : nullptr;
        const float* qB2 = (r2B != 0xFFFFu) ? (rpf + (size_t)r2B * 200) : nullptr;
        float zA = s1n + s2A + srA, zB = s1n + s2B + srB;
        float wA = expf(-(zA > 0.f ? zA : 0.2f * zA));
        float wB = expf(-(zB > 0.f ? zB : 0.2f * zB));
        rs += wA + wB;
#pragma unroll
        for (int s = 0; s < 4; s++) {
            int k = lane + 64 * s;
            if (k < 200) {
                float vA = toF(xA[k]) + qA1[k] + (qA2 ? qA2[k] : 0.f);
                float vB = toF(xB[k]) + qB1[k] + (qB2 ? qB2[k] : 0.f);
                a[s] += wA * vA + wB * vB;
            }
        }
    }
    if (idx < b1) {
        int2 eg = csr[idx];
        unsigned ey = (unsigned)eg.y;
        int r1 = (int)(ey & 0xFFFFu);
        unsigned r2 = ey >> 16;
        const __hip_bfloat16* xs = x1A2 + (size_t)eg.x * PBS;
        float s2v = *(const float*)(xs + 200);
        float sr = srel[r1] + (r2 != 0xFFFFu ? srel[(int)r2] : 0.f);
        float z = s1n + s2v + sr;
        float w = expf(-(z > 0.f ? z : 0.2f * z));
        rs += w;
        const float* q1 = rpf + (size_t)r1 * 200;
        const float* q2 = (r2 != 0xFFFFu) ? (rpf + (size_t)r2 * 200) : nullptr;
#pragma unroll
        for (int s = 0; s < 4; s++) {
            int k = lane + 64 * s;
            if (k < 200) {
                float v = toF(xs[k]) + q1[k] + (q2 ? q2[k] : 0.f);
                a[s] += w * v;
            }
        }
    }

    float inv = rs > 0.f ? 1.f / rs : 0.f;
    float mk = maskf[n];
    float* orow = outent + (size_t)n * 200;
#pragma unroll
    for (int s = 0; s < 4; s++) {
        int k = lane + 64 * s;
        if (k < 200) {
            float hp = rs > 0.f ? orow[k] + a[s] * inv : 0.f;
            float e = hp > 0.f ? hp : expf(hp) - 1.f;
            orow[k] = mk * e;
        }
    }
}

__global__ void scatter_mask_k(const int* __restrict__ batch, int NB,
                               float* __restrict__ masko)
{
    int i = blockIdx.x * blockDim.x + threadIdx.x;
    if (i >= NB) return;
    masko[batch[i]] = 1.0f;
}

extern "C" void kernel_launch(void* const* d_in, const int* in_sizes, int n_in,
                              void* d_out, int out_size, void* d_ws, size_t ws_size,
                              hipStream_t stream)
{
    const float* ent      = (const float*)d_in[0];
    const float* rel      = (const float*)d_in[1];
    const float* W_ent    = (const float*)d_in[2];
    const float* W_gat    = (const float*)d_in[3];
    const float* a_heads  = (const float*)d_in[4];
    const float* a2_heads = (const float*)d_in[5];
    const float* a_out    = (const float*)d_in[6];
    const float* a2_out   = (const float*)d_in[7];
    const int* batch = (const int*)d_in[8];
    const int* el    = (const int*)d_in[9];
    const int* etype = (const int*)d_in[10];
    const int* tin   = (const int*)d_in[11];

    const int N   = in_sizes[0] / DD;   // 50000
    const int R   = in_sizes[1] / DD;   // 500
    const int NB  = in_sizes[8];        // 20000
    const int E   = in_sizes[9] / 2;    // 150000
    const int ENH = in_sizes[11] / 4;   // 30000
    const int Etot = E + ENH;

    // ---- workspace ----
    char* ws = (char*)d_ws;
    size_t off = 0;
    auto take = [&](size_t bytes) { size_t o = off; off += (bytes + 255) & ~(size_t)255; return o; };
    size_t o_R1   = take((size_t)N * KP * 2);     // x1 bf16 [N][KP]
    size_t o_R2   = take((size_t)N * PBS * 2);    // pB [N][PBS]; later x1A2 [N][PBS]
    size_t o_rpf  = take((size_t)2 * R * 100 * 4);// rpf2 [2][R][100] / layer2 rpf [R][200]
    size_t o_bt1  = take((size_t)400 * KP * 2);
    size_t o_bt2  = take((size_t)400 * KP * 2);
    size_t o_btf  = take((size_t)208 * KP * 2);
    size_t o_nsc  = take((size_t)N * 4);
    size_t o_s1   = take((size_t)2 * N * 4);      // aliased by cnt during CSR build
    size_t o_srel = take((size_t)2 * R * 4);
    size_t o_csr  = take((size_t)Etot * 8);
    size_t o_str  = take((size_t)(N + 1) * 4);
    size_t o_aux  = take((size_t)64 * 4);

    __hip_bfloat16* x1   = (__hip_bfloat16*)(ws + o_R1);
    __hip_bfloat16* pB   = (__hip_bfloat16*)(ws + o_R2);
    __hip_bfloat16* x1A2 = (__hip_bfloat16*)(ws + o_R2);
    float* rpf2   = (float*)(ws + o_rpf);
    __hip_bfloat16* bt1 = (__hip_bfloat16*)(ws + o_bt1);
    __hip_bfloat16* bt2 = (__hip_bfloat16*)(ws + o_bt2);
    __hip_bfloat16* btf = (__hip_bfloat16*)(ws + o_btf);
    float* nscale = (float*)(ws + o_nsc);
    float* s1     = (float*)(ws + o_s1);
    float* srel2  = (float*)(ws + o_srel);
    int2*  csr    = (int2*)(ws + o_csr);
    int*   cnt    = (int*)(ws + o_s1);   // CSR-build scratch; dead before l1_both_k writes s1
    int*   startA = (int*)(ws + o_str);
    int*   aux    = (int*)(ws + o_aux);

    float* out       = (float*)d_out;
    float* out_ent   = out;                                     // [N,200]
    float* out_rel_o = out + (size_t)N * OD;                    // [500,200]
    float* out_mask  = out + (size_t)N * OD + (size_t)R * OD;   // [N]

    const int nblk = cdiv(N, 64);
    const int nbScan = cdiv(N, 1024);

    // A. prep: norms, B panels, x1 pad; out_rel GEMM
    rownorm_inv_k<<<cdiv(N, 4), 256, 0, stream>>>(ent, nscale, N, DD);
    prep_bt_l1<<<400, 256, 0, stream>>>(a_heads, bt1);
    prep_bt_l2<<<400, 256, 0, stream>>>(a_out, bt2);
    prep_bt_fin<<<208, 256, 0, stream>>>(W_ent, btf);
    hipMemsetAsync(x1, 0, (size_t)N * KP * 2, stream);
    gemm_mfma_k<false, float, float><<<dim3(cdiv(OD, 64), cdiv(R, 64)), 256, 0, stream>>>(
        rel, DD, nullptr, W_gat, OD, 0, out_rel_o, OD, R, OD, DD);

    // A2. CSR build (dst-grouped edge lists)
    hipMemsetAsync(cnt, 0, (size_t)N * 4, stream);
    hist_k<<<cdiv(Etot, 256), 256, 0, stream>>>(el, E, etype, tin, Etot, cnt);
    scan1_k<<<nbScan, 1024, 0, stream>>>(cnt, startA, aux, N);
    scan2_k<<<1, 64, 0, stream>>>(aux, nbScan);
    scan3_k<<<nbScan, 1024, 0, stream>>>(startA, aux, N, Etot);
    hipMemsetAsync(cnt, 0, (size_t)N * 4, stream);
    fill_k<<<cdiv(Etot, 256), 256, 0, stream>>>(el, E, etype, tin, Etot, startA, cnt, csr);

    // B. layer-1 projections (both heads) + rel projections + gather
    l1_both_k<<<nblk, 256, 0, stream>>>(ent, nscale, bt1, a2_heads, x1, pB, s1, N);
    for (int h = 0; h < 2; h++) {
        const float* ah  = a_heads + (size_t)h * NHID * 600;
        const float* a2h = a2_heads + (size_t)h * NHID;
        gemm_mfma_k<true, float, float><<<dim3(cdiv(NHID, 64), cdiv(R, 64)), 256, 0, stream>>>(
            rel, DD, nullptr, ah, 600, 400, rpf2 + (size_t)h * R * NHID, NHID, R, NHID, DD);
        rowdot_k<float><<<cdiv(R, 4), 256, 0, stream>>>(
            rpf2 + (size_t)h * R * NHID, NHID, 0, a2h, srel2 + (size_t)h * R, R, NHID);
    }
    gather_l1_k<<<cdiv(N, 4), 256, 0, stream>>>(
        startA, csr, s1, srel2, R, pB, rpf2, x1, N);
    // pB dead; R2 becomes x1A2.

    // C. layer-2 projection + rel side
    l2_proj_k<<<nblk, 256, 0, stream>>>(x1, bt2, a2_out, out_ent, x1A2, s1, N);
    gemm_mfma_k<true, float, float><<<dim3(cdiv(OD, 64), cdiv(R, 64)), 256, 0, stream>>>(
        out_rel_o, OD, nullptr, a_out, 600, 400, rpf2, OD, R, OD, OD);
    rowdot_k<float><<<cdiv(R, 4), 256, 0, stream>>>(rpf2, OD, 0, a2_out, srel2, R, OD);

    // D. mask; layer-2 gather (fused combine, single 200-wide pass)
    hipMemsetAsync(out_mask, 0, (size_t)N * 4, stream);
    scatter_mask_k<<<cdiv(NB, 256), 256, 0, stream>>>(batch, NB, out_mask);
    gather_l2_k<<<cdiv(N, 4), 256, 0, stream>>>(
        startA, csr, s1, srel2, x1A2, rpf2, out_mask, out_ent, N);

    // E. fused final GEMM + l2norm
    final_mfma_k<<<nblk, 256, 0, stream>>>(ent, nscale, btf, out_ent, N);
}